// Round 4
// baseline (201.530 us; speedup 1.0000x reference)
//
#include <hip/hip_runtime.h>
#include <stdint.h>

typedef unsigned short u16;
typedef short short4v __attribute__((ext_vector_type(4)));
typedef short short8v __attribute__((ext_vector_type(8)));
typedef float float4v __attribute__((ext_vector_type(4)));

#define AS1(p) ((__attribute__((address_space(1))) void*)(p))
#define AS3(p) ((__attribute__((address_space(3))) void*)(p))

#define MFMA32(a, b, c) __builtin_amdgcn_mfma_f32_16x16x32_bf16(a, b, c, 0, 0, 0)

static __device__ __forceinline__ float4v MFMA16(short4v a, short4v b, float4v c) {
#if __has_builtin(__builtin_amdgcn_mfma_f32_16x16x16bf16_1k)
  return __builtin_amdgcn_mfma_f32_16x16x16bf16_1k(a, b, c, 0, 0, 0);
#else
  float4v d;
  asm volatile("v_mfma_f32_16x16x16_bf16 %0, %1, %2, %3\n\ts_nop 7\n\ts_nop 3"
               : "=v"(d)
               : "v"(a), "v"(b), "v"(c));
  return d;
#endif
}

static __device__ __forceinline__ u16 f2bf(float f) {
  uint32_t u = __builtin_bit_cast(uint32_t, f);
  u += 0x7FFFu + ((u >> 16) & 1u);
  return (u16)(u >> 16);
}

static __device__ __forceinline__ unsigned cvtpk(float lo, float hi) {
  unsigned r;
  asm("v_cvt_pk_bf16_f32 %0, %1, %2" : "=v"(r) : "v"(lo), "v"(hi));
  return r;
}

#define TR4(v0_, v1_, v2_, v3_, addr_)                                   \
  asm volatile("ds_read_b64_tr_b16 %0, %4 offset:0\n\t"                  \
               "ds_read_b64_tr_b16 %1, %4 offset:2048\n\t"               \
               "ds_read_b64_tr_b16 %2, %4 offset:4096\n\t"               \
               "ds_read_b64_tr_b16 %3, %4 offset:6144\n\t"               \
               "s_waitcnt lgkmcnt(0)"                                    \
               : "=&v"(v0_), "=&v"(v1_), "=&v"(v2_), "=&v"(v3_)          \
               : "v"(addr_)                                              \
               : "memory")

// ---------------- f32 -> bf16 casts ----------------

__global__ __launch_bounds__(256) void cast1_k(const float* __restrict__ s, u16* __restrict__ d) {
  const int i = (blockIdx.x * 256 + threadIdx.x) * 4;
  float4v v = *(const float4v*)(s + i);
  short4v o;
#pragma unroll
  for (int j = 0; j < 4; j++) o[j] = (short)f2bf(v[j]);
  *(short4v*)(d + i) = o;
}

__global__ __launch_bounds__(256) void cast4_k(const float* __restrict__ s0, const float* __restrict__ s1,
                                               const float* __restrict__ s2, const float* __restrict__ s3,
                                               u16* __restrict__ d0, u16* __restrict__ d1,
                                               u16* __restrict__ d2, u16* __restrict__ d3) {
  const float* s;
  u16* d;
  switch (blockIdx.y) {
    case 0: s = s0; d = d0; break;
    case 1: s = s1; d = d1; break;
    case 2: s = s2; d = d2; break;
    default: s = s3; d = d3; break;
  }
  const int i = (blockIdx.x * 256 + threadIdx.x) * 4;
  float4v v = *(const float4v*)(s + i);
  short4v o;
#pragma unroll
  for (int j = 0; j < 4; j++) o[j] = (short)f2bf(v[j]);
  *(short4v*)(d + i) = o;
}

// ---------------- 256x256-tile 8-wave pipelined GEMM (QKV) ----------------
// C[m,n] = (sum_k A[m,k]*B[n,k] + bias[n]) * scale, bf16 out.
// BK=32 K-subtiles in a 4-buffer LDS ring ([x][32] layout = zero bank conflict).
// 4 phases/iter (2 K-subtiles), counted vmcnt(4) (T4), setprio (T5), 2 bar/phase (T3).
// Prefetch distance = 4 phases; vmcnt never 0 in main loop.

__global__ __launch_bounds__(512, 2) void gemm256(
    const u16* __restrict__ A,
    const u16* __restrict__ B0, const u16* __restrict__ B1, const u16* __restrict__ B2,
    const float* __restrict__ bias0, const float* __restrict__ bias1, const float* __restrict__ bias2,
    u16* __restrict__ C0, u16* __restrict__ C1, u16* __restrict__ C2,
    float sc0, float sc1, float sc2) {
  constexpr int K = 1024;
  __shared__ u16 As[4][256][32];
  __shared__ u16 Bs[4][256][32];

  const int t = threadIdx.x;
  const int lane = t & 63, wid = t >> 6;
  const int wm = wid >> 2, wn = wid & 3;   // 2 x 4 wave grid; wave tile 128x64
  const int lr = lane & 15, g = lane >> 4;

  // XCD-rect swizzle: 192 blocks = 8 XCDs x 24; rect = 4 mb x 6 nbt
  const int id = blockIdx.x;
  const int xc = id & 7, off = id >> 3;
  const int mb = (xc & 3) * 4 + (off & 3);
  const int nbt = (xc >> 2) * 6 + (off >> 2);
  const int seg = nbt >> 2, nb = nbt & 3;

  const u16* Bm = seg == 0 ? B0 : (seg == 1 ? B1 : B2);
  const float* bias = seg == 0 ? bias0 : (seg == 1 ? bias1 : bias2);
  u16* C = seg == 0 ? C0 : (seg == 1 ? C1 : C2);
  const float scale = seg == 0 ? sc0 : (seg == 1 ? sc1 : sc2);

  const u16* Ap = A + (size_t)mb * 256 * K;
  const u16* Bp = Bm + (size_t)nb * 256 * K;

  float4v z = {0.f, 0.f, 0.f, 0.f};
  float4v acc[8][4];
#pragma unroll
  for (int i = 0; i < 8; i++)
#pragma unroll
    for (int j = 0; j < 4; j++) acc[i][j] = z;

  // staging: thread t covers rows ar0 and ar0+128, 8-col chunk ac0, of a [256][32] subtile
  const int ar0 = t >> 2, ar1 = ar0 + 128, ac0 = (t & 3) * 8;

#define STGA(rg, kb)                                                                                              \
  {                                                                                                               \
    __builtin_amdgcn_global_load_lds(AS1(Ap + (size_t)ar0 * K + (kb) + ac0), AS3(&As[rg][ar0][ac0]), 16, 0, 0);   \
    __builtin_amdgcn_global_load_lds(AS1(Ap + (size_t)ar1 * K + (kb) + ac0), AS3(&As[rg][ar1][ac0]), 16, 0, 0);   \
  }
#define STGB(rg, kb)                                                                                              \
  {                                                                                                               \
    __builtin_amdgcn_global_load_lds(AS1(Bp + (size_t)ar0 * K + (kb) + ac0), AS3(&Bs[rg][ar0][ac0]), 16, 0, 0);   \
    __builtin_amdgcn_global_load_lds(AS1(Bp + (size_t)ar1 * K + (kb) + ac0), AS3(&Bs[rg][ar1][ac0]), 16, 0, 0);   \
  }
#define VM4 asm volatile("s_waitcnt vmcnt(4)" ::: "memory")
#define VM0 asm volatile("s_waitcnt vmcnt(0)" ::: "memory")

// One phase: 8 ds_read_b128 -> stage -> (vmcnt) -> bar -> lgkmcnt(0) -> 16 MFMA -> bar
#define PH(rg, mq, STG_, VM_)                                                         \
  {                                                                                   \
    short8v a_[4], b_[4];                                                             \
    _Pragma("unroll") for (int i = 0; i < 4; i++)                                     \
        a_[i] = *(const short8v*)&As[rg][wm * 128 + ((mq)*4 + i) * 16 + lr][g * 8];   \
    _Pragma("unroll") for (int j = 0; j < 4; j++)                                     \
        b_[j] = *(const short8v*)&Bs[rg][wn * 64 + j * 16 + lr][g * 8];               \
    STG_;                                                                             \
    VM_;                                                                              \
    __builtin_amdgcn_s_barrier();                                                     \
    asm volatile("s_waitcnt lgkmcnt(0)");                                             \
    __builtin_amdgcn_sched_barrier(0);                                                \
    __builtin_amdgcn_s_setprio(1);                                                    \
    _Pragma("unroll") for (int i = 0; i < 4; i++)                                     \
        _Pragma("unroll") for (int j = 0; j < 4; j++)                                 \
            acc[(mq)*4 + i][j] = MFMA32(a_[i], b_[j], acc[(mq)*4 + i][j]);            \
    __builtin_amdgcn_s_setprio(0);                                                    \
    __builtin_amdgcn_s_barrier();                                                     \
    __builtin_amdgcn_sched_barrier(0);                                                \
  }

  // prologue: stage K-subtiles 0,1 into rings 0,1; first subtile must be landed
  STGA(0, 0);
  STGB(0, 0);
  STGA(1, 32);
  STGB(1, 32);
  VM4;
  __builtin_amdgcn_s_barrier();

  for (int it = 0; it < 15; ++it) {
    const int r0 = (it & 1) << 1, r1 = r0 + 1;          // rings computed this iter
    const int rn2 = ((it + 1) & 1) << 1, rn3 = rn2 + 1; // rings staged this iter
    const int kb2 = it * 64 + 64, kb3 = kb2 + 32;
    PH(r0, 0, STGA(rn2, kb2), );
    PH(r0, 1, STGB(rn2, kb2), VM4);
    PH(r1, 0, STGA(rn3, kb3), );
    PH(r1, 1, STGB(rn3, kb3), VM4);
  }
  // epilogue iter (K-subtiles 30,31), no staging; one full drain before ring 3
  PH(2, 0, , );
  PH(2, 1, , VM0);
  PH(3, 0, , );
  PH(3, 1, , );

#undef PH
#undef STGA
#undef STGB

  const int colb = nb * 256 + wn * 64;
  const int rowb = mb * 256 + wm * 128;
#pragma unroll
  for (int j = 0; j < 4; j++) {
    const int col = colb + j * 16 + lr;
    const float bv = bias[col];
#pragma unroll
    for (int i = 0; i < 8; i++) {
      const int row0 = rowb + i * 16 + g * 4;
#pragma unroll
      for (int r = 0; r < 4; r++)
        C[(size_t)(row0 + r) * 1024 + col] = f2bf((acc[i][j][r] + bv) * scale);
    }
  }
}

// ---------------- GEMM (output projection): 128x128 tile, 2-phase dbuf ----------------

template <int OUTF32>
__global__ __launch_bounds__(256) void gemm_bt(
    const u16* __restrict__ A,
    const u16* __restrict__ B0, const u16* __restrict__ B1, const u16* __restrict__ B2,
    const float* __restrict__ bias0, const float* __restrict__ bias1, const float* __restrict__ bias2,
    void* __restrict__ C0, void* __restrict__ C1, void* __restrict__ C2,
    float sc0, float sc1, float sc2) {
  constexpr int K = 1024;
  __shared__ u16 As[2][128 * 32];
  __shared__ u16 Bs[2][128 * 32];

  const int t = threadIdx.x;
  const int lane = t & 63, wid = t >> 6;
  const int wr = wid >> 1, wc = wid & 1;
  const int lr = lane & 15, g = lane >> 4;

  const int seg = blockIdx.y >> 3, nb = blockIdx.y & 7, mb = blockIdx.x;
  const u16* B = seg == 0 ? B0 : (seg == 1 ? B1 : B2);
  const float* bias = seg == 0 ? bias0 : (seg == 1 ? bias1 : bias2);
  void* C = seg == 0 ? C0 : (seg == 1 ? C1 : C2);
  const float scale = seg == 0 ? sc0 : (seg == 1 ? sc1 : sc2);

  const u16* Ap = A + (size_t)mb * 128 * K;
  const u16* Bp = B + (size_t)nb * 128 * K;

  float4v z = {0.f, 0.f, 0.f, 0.f};
  float4v acc[4][4];
#pragma unroll
  for (int i = 0; i < 4; i++)
#pragma unroll
    for (int j = 0; j < 4; j++) acc[i][j] = z;

  const int r0 = t >> 2, c0 = (t & 3) * 8;

#define GSTAGE(u, kk)                                                                                          \
  do {                                                                                                         \
    __builtin_amdgcn_global_load_lds(AS1(Ap + (size_t)r0 * K + (kk) + c0), AS3(&As[u][t * 8]), 16, 0, 0);      \
    __builtin_amdgcn_global_load_lds(AS1(Ap + (size_t)(r0 + 64) * K + (kk) + c0), AS3(&As[u][(t + 256) * 8]),  \
                                     16, 0, 0);                                                                \
    __builtin_amdgcn_global_load_lds(AS1(Bp + (size_t)r0 * K + (kk) + c0), AS3(&Bs[u][t * 8]), 16, 0, 0);      \
    __builtin_amdgcn_global_load_lds(AS1(Bp + (size_t)(r0 + 64) * K + (kk) + c0), AS3(&Bs[u][(t + 256) * 8]),  \
                                     16, 0, 0);                                                                \
  } while (0)

  GSTAGE(0, 0);
  int cur = 0;
  for (int k0 = 0; k0 < K; k0 += 32) {
    __syncthreads();
    if (k0 + 32 < K) GSTAGE(cur ^ 1, k0 + 32);

    const u16* Au = &As[cur][0];
    const u16* Bu = &Bs[cur][0];
    short8v af[4], bfr[4];
#pragma unroll
    for (int mi = 0; mi < 4; mi++) af[mi] = *(const short8v*)(Au + (wr * 64 + mi * 16 + lr) * 32 + g * 8);
#pragma unroll
    for (int ni = 0; ni < 4; ni++) bfr[ni] = *(const short8v*)(Bu + (wc * 64 + ni * 16 + lr) * 32 + g * 8);
    __builtin_amdgcn_s_setprio(1);
#pragma unroll
    for (int mi = 0; mi < 4; mi++)
#pragma unroll
      for (int ni = 0; ni < 4; ni++) acc[mi][ni] = MFMA32(af[mi], bfr[ni], acc[mi][ni]);
    __builtin_amdgcn_s_setprio(0);
    __syncthreads();
    cur ^= 1;
  }
#undef GSTAGE

  const int colb = nb * 128 + wc * 64;
  const int rowb = mb * 128 + wr * 64;
#pragma unroll
  for (int ni = 0; ni < 4; ni++) {
    const int col = colb + ni * 16 + lr;
    const float bv = bias[col];
#pragma unroll
    for (int mi = 0; mi < 4; mi++) {
      const int row0 = rowb + mi * 16 + g * 4;
      float4v a = acc[mi][ni];
      if (OUTF32) {
        float* Cf = (float*)C;
#pragma unroll
        for (int r = 0; r < 4; r++) Cf[(size_t)(row0 + r) * 1024 + col] = (a[r] + bv) * scale;
      } else {
        u16* Cb = (u16*)C;
#pragma unroll
        for (int r = 0; r < 4; r++) Cb[(size_t)(row0 + r) * 1024 + col] = f2bf((a[r] + bv) * scale);
      }
    }
  }
}

// ---------------- Flash attention (R2 config: QBLK=64) ----------------

__global__ __launch_bounds__(256) void attn_fwd(const u16* __restrict__ Qm, const u16* __restrict__ Km,
                                                const u16* __restrict__ Vm, u16* __restrict__ Om) {
  __shared__ u16 Ks[2][64 * 64];
  __shared__ u16 Vs[2][64 * 64];

  const int t = threadIdx.x;
  const int lane = t & 63, w = t >> 6;
  const int lr = lane & 15, g = lane >> 4;
  const int qb = blockIdx.x, pair = blockIdx.y;
  const int b = pair >> 4, a = pair & 15;

  const int qrow = qb * 64 + w * 16 + lr;
  const size_t qoff = ((size_t)(b * 1024 + qrow)) * 1024 + a * 64;
  const short8v qf0 = *(const short8v*)(Qm + qoff + g * 8);
  const short8v qf1 = *(const short8v*)(Qm + qoff + 32 + g * 8);

  float4v z = {0.f, 0.f, 0.f, 0.f};
  float4v ot[4];
#pragma unroll
  for (int i = 0; i < 4; i++) ot[i] = z;
  float mrun = -3.0e38f, lsum = 0.f;

  const u16* Kb = Km + ((size_t)b * 1024) * 1024 + a * 64;
  const u16* Vb = Vm + ((size_t)b * 1024) * 1024 + a * 64;

  const int kr0 = t >> 3, kr1 = kr0 + 32;
  const int kc0 = ((t & 7) ^ (kr0 & 7)) * 8;
  const int vr0 = (t >> 1) & 63;
  const int vc0 = (t >> 7) * 16 + (t & 1) * 8;

#define ASTAGE(u, kt)                                                                                             \
  do {                                                                                                            \
    __builtin_amdgcn_global_load_lds(AS1(Kb + (size_t)((kt) + kr0) * 1024 + kc0), AS3(&Ks[u][t * 8]), 16, 0, 0);  \
    __builtin_amdgcn_global_load_lds(AS1(Kb + (size_t)((kt) + kr1) * 1024 + kc0), AS3(&Ks[u][(t + 256) * 8]),     \
                                     16, 0, 0);                                                                   \
    __builtin_amdgcn_global_load_lds(AS1(Vb + (size_t)((kt) + vr0) * 1024 + vc0), AS3(&Vs[u][t * 8]), 16, 0, 0);  \
    __builtin_amdgcn_global_load_lds(AS1(Vb + (size_t)((kt) + vr0) * 1024 + vc0 + 32), AS3(&Vs[u][(t + 256) * 8]),\
                                     16, 0, 0);                                                                   \
  } while (0)

  const unsigned vsbase = (unsigned)(uintptr_t)AS3(&Vs[0][0]);
  const unsigned vlane = (unsigned)((g * 4 + (lr >> 2)) * 32 + (lane & 3) * 8);

  ASTAGE(0, 0);
  int cur = 0;
  for (int kt = 0; kt < 1024; kt += 64) {
    __syncthreads();
    if (kt + 64 < 1024) ASTAGE(cur ^ 1, kt + 64);

    const u16* Ku = &Ks[cur][0];
    float4v st[4];
#pragma unroll
    for (int jt = 0; jt < 4; jt++) {
      float4v s = z;
      const int row = jt * 16 + lr;
      const int rsw = (row & 7) << 4;
      __builtin_amdgcn_s_setprio(1);
#pragma unroll
      for (int ks = 0; ks < 2; ks++) {
        const int baddr = (row * 128 + (ks * 4 + g) * 16) ^ rsw;
        short8v kf = *(const short8v*)((const char*)Ku + baddr);
        s = MFMA32(kf, ks ? qf1 : qf0, s);
      }
      __builtin_amdgcn_s_setprio(0);
      st[jt] = s;
    }

    float tm = st[0][0];
#pragma unroll
    for (int jt = 0; jt < 4; jt++)
#pragma unroll
      for (int r = 0; r < 4; r++) tm = fmaxf(tm, st[jt][r]);
    tm = fmaxf(tm, __shfl_xor(tm, 16));
    tm = fmaxf(tm, __shfl_xor(tm, 32));
    if (!__all(tm - mrun <= 8.f)) {
      const float mnew = fmaxf(mrun, tm);
      const float sca = exp2f(mrun - mnew);
      lsum *= sca;
#pragma unroll
      for (int d = 0; d < 4; d++)
#pragma unroll
        for (int r = 0; r < 4; r++) ot[d][r] *= sca;
      mrun = mnew;
    }
    float p[16];
    float ts = 0.f;
#pragma unroll
    for (int jt = 0; jt < 4; jt++)
#pragma unroll
      for (int r = 0; r < 4; r++) {
        const float pv = exp2f(st[jt][r] - mrun);
        p[jt * 4 + r] = pv;
        ts += pv;
      }
    ts += __shfl_xor(ts, 16);
    ts += __shfl_xor(ts, 32);
    lsum += ts;

    short4v pf[4];
#pragma unroll
    for (int jt = 0; jt < 4; jt++) {
      unsigned lo = cvtpk(p[jt * 4 + 0], p[jt * 4 + 1]);
      unsigned hi = cvtpk(p[jt * 4 + 2], p[jt * 4 + 3]);
      unsigned u2[2] = {lo, hi};
      pf[jt] = __builtin_bit_cast(short4v, *(unsigned long long*)u2);
    }

    unsigned va = vsbase + (unsigned)cur * 8192u + vlane;
#pragma unroll
    for (int jt = 0; jt < 4; jt++) {
      short4v vf0, vf1, vf2, vf3;
      TR4(vf0, vf1, vf2, vf3, va);
      __builtin_amdgcn_s_setprio(1);
      ot[0] = MFMA16(vf0, pf[jt], ot[0]);
      ot[1] = MFMA16(vf1, pf[jt], ot[1]);
      ot[2] = MFMA16(vf2, pf[jt], ot[2]);
      ot[3] = MFMA16(vf3, pf[jt], ot[3]);
      __builtin_amdgcn_s_setprio(0);
      va += 512u;
    }

    __syncthreads();
    cur ^= 1;
  }
#undef ASTAGE

  const float inv = 1.f / lsum;
  u16* Op = Om + ((size_t)(b * 1024 + qrow)) * 1024 + a * 64;
#pragma unroll
  for (int dblk = 0; dblk < 4; dblk++) {
    short4v o4;
#pragma unroll
    for (int r = 0; r < 4; r++) o4[r] = (short)f2bf(ot[dblk][r] * inv);
    *(short4v*)(Op + dblk * 16 + g * 4) = o4;
  }
}

// ---------------- launch ----------------

extern "C" void kernel_launch(void* const* d_in, const int* in_sizes, int n_in,
                              void* d_out, int out_size, void* d_ws, size_t ws_size,
                              hipStream_t stream) {
  (void)in_sizes; (void)n_in; (void)out_size; (void)ws_size;
  const float* x = (const float*)d_in[0];
  const float* Wq = (const float*)d_in[1];
  const float* bq = (const float*)d_in[2];
  const float* Wk = (const float*)d_in[3];
  const float* bk = (const float*)d_in[4];
  const float* Wv = (const float*)d_in[5];
  const float* bv = (const float*)d_in[6];
  const float* Wo = (const float*)d_in[7];
  const float* bo = (const float*)d_in[8];
  float* out = (float*)d_out;

  char* ws = (char*)d_ws;
  const size_t MB = 1u << 20;
  u16* xb = (u16*)(ws + 0 * MB);
  u16* Wqb = (u16*)(ws + 8 * MB);
  u16* Wkb = (u16*)(ws + 10 * MB);
  u16* Wvb = (u16*)(ws + 12 * MB);
  u16* Wob = (u16*)(ws + 14 * MB);
  u16* Qb = (u16*)(ws + 16 * MB);
  u16* Kb = (u16*)(ws + 24 * MB);
  u16* Vb = (u16*)(ws + 32 * MB);
  u16* Ab = (u16*)(ws + 40 * MB);

  const float csc = 1.4426950408889634f / 8.0f;  // log2(e)/sqrt(HEAD_DIM)

  cast1_k<<<4096, 256, 0, stream>>>(x, xb);
  cast4_k<<<dim3(1024, 4), 256, 0, stream>>>(Wq, Wk, Wv, Wo, Wqb, Wkb, Wvb, Wob);
  gemm256<<<192, 512, 0, stream>>>(xb, Wqb, Wkb, Wvb, bq, bk, bv, Qb, Kb, Vb, csc, 1.f, 1.f);
  attn_fwd<<<dim3(16, 64), 256, 0, stream>>>(Qb, Kb, Vb, Ab);
  gemm_bt<1><<<dim3(32, 8), 256, 0, stream>>>(Ab, Wob, Wob, Wob, bo, bo, bo, out, out, out, 1.f, 1.f, 1.f);
}

// Round 5
// 195.351 us; speedup vs baseline: 1.0316x; 1.0316x over previous
//
#include <hip/hip_runtime.h>
#include <stdint.h>

typedef unsigned short u16;
typedef short short4v __attribute__((ext_vector_type(4)));
typedef short short8v __attribute__((ext_vector_type(8)));
typedef float float4v __attribute__((ext_vector_type(4)));

#define AS1(p) ((__attribute__((address_space(1))) void*)(p))
#define AS3(p) ((__attribute__((address_space(3))) void*)(p))

#define MFMA32(a, b, c) __builtin_amdgcn_mfma_f32_16x16x32_bf16(a, b, c, 0, 0, 0)

static __device__ __forceinline__ float4v MFMA16(short4v a, short4v b, float4v c) {
#if __has_builtin(__builtin_amdgcn_mfma_f32_16x16x16bf16_1k)
  return __builtin_amdgcn_mfma_f32_16x16x16bf16_1k(a, b, c, 0, 0, 0);
#else
  float4v d;
  asm volatile("v_mfma_f32_16x16x16_bf16 %0, %1, %2, %3\n\ts_nop 7\n\ts_nop 3"
               : "=v"(d)
               : "v"(a), "v"(b), "v"(c));
  return d;
#endif
}

static __device__ __forceinline__ u16 f2bf(float f) {
  uint32_t u = __builtin_bit_cast(uint32_t, f);
  u += 0x7FFFu + ((u >> 16) & 1u);
  return (u16)(u >> 16);
}

static __device__ __forceinline__ unsigned cvtpk(float lo, float hi) {
  unsigned r;
  asm("v_cvt_pk_bf16_f32 %0, %1, %2" : "=v"(r) : "v"(lo), "v"(hi));
  return r;
}

#define TR4(v0_, v1_, v2_, v3_, addr_)                                   \
  asm volatile("ds_read_b64_tr_b16 %0, %4 offset:0\n\t"                  \
               "ds_read_b64_tr_b16 %1, %4 offset:2048\n\t"               \
               "ds_read_b64_tr_b16 %2, %4 offset:4096\n\t"               \
               "ds_read_b64_tr_b16 %3, %4 offset:6144\n\t"               \
               "s_waitcnt lgkmcnt(0)"                                    \
               : "=&v"(v0_), "=&v"(v1_), "=&v"(v2_), "=&v"(v3_)          \
               : "v"(addr_)                                              \
               : "memory")

// ---------------- f32 -> bf16 casts ----------------

__global__ __launch_bounds__(256) void cast1_k(const float* __restrict__ s, u16* __restrict__ d) {
  const int i = (blockIdx.x * 256 + threadIdx.x) * 4;
  float4v v = *(const float4v*)(s + i);
  short4v o;
#pragma unroll
  for (int j = 0; j < 4; j++) o[j] = (short)f2bf(v[j]);
  *(short4v*)(d + i) = o;
}

__global__ __launch_bounds__(256) void cast4_k(const float* __restrict__ s0, const float* __restrict__ s1,
                                               const float* __restrict__ s2, const float* __restrict__ s3,
                                               u16* __restrict__ d0, u16* __restrict__ d1,
                                               u16* __restrict__ d2, u16* __restrict__ d3) {
  const float* s;
  u16* d;
  switch (blockIdx.y) {
    case 0: s = s0; d = d0; break;
    case 1: s = s1; d = d1; break;
    case 2: s = s2; d = d2; break;
    default: s = s3; d = d3; break;
  }
  const int i = (blockIdx.x * 256 + threadIdx.x) * 4;
  float4v v = *(const float4v*)(s + i);
  short4v o;
#pragma unroll
  for (int j = 0; j < 4; j++) o[j] = (short)f2bf(v[j]);
  *(short4v*)(d + i) = o;
}

// ---------------- 256x256-tile 8-wave pipelined GEMM (QKV) ----------------
// Ring of 4 BK=32 K-subtiles; stage ring r+3 while computing r (prefetch ~6
// phases ahead); steady-state vmcnt(8) (T4: never 0 in main loop).
// T2 both-sides chunk swizzle: physical 16B chunk = c ^ ((row>>1)&3)
// (applied on the per-lane GLOBAL source + on ds_read addr; LDS dest linear,
// per rule #21). Bank map: 2-way only = free.

__global__ __launch_bounds__(512, 2) void gemm256(
    const u16* __restrict__ A,
    const u16* __restrict__ B0, const u16* __restrict__ B1, const u16* __restrict__ B2,
    const float* __restrict__ bias0, const float* __restrict__ bias1, const float* __restrict__ bias2,
    u16* __restrict__ C0, u16* __restrict__ C1, u16* __restrict__ C2,
    float sc0, float sc1, float sc2) {
  constexpr int K = 1024;
  __shared__ u16 As[4][256][32];
  __shared__ u16 Bs[4][256][32];

  const int t = threadIdx.x;
  const int lane = t & 63, wid = t >> 6;
  const int wm = wid >> 2, wn = wid & 3;  // 2 x 4 wave grid; wave tile 128x64
  const int lr = lane & 15, g = lane >> 4;

  // XCD-rect swizzle: 192 blocks = 8 XCDs x 24; rect = 4 mb x 6 nbt
  const int id = blockIdx.x;
  const int xc = id & 7, off = id >> 3;
  const int mb = (xc & 3) * 4 + (off & 3);
  const int nbt = (xc >> 2) * 6 + (off >> 2);
  const int seg = nbt >> 2, nb = nbt & 3;

  const u16* Bm = seg == 0 ? B0 : (seg == 1 ? B1 : B2);
  const float* bias = seg == 0 ? bias0 : (seg == 1 ? bias1 : bias2);
  u16* C = seg == 0 ? C0 : (seg == 1 ? C1 : C2);
  const float scale = seg == 0 ? sc0 : (seg == 1 ? sc1 : sc2);

  const u16* Ap = A + (size_t)mb * 256 * K;
  const u16* Bp = Bm + (size_t)nb * 256 * K;

  float4v z = {0.f, 0.f, 0.f, 0.f};
  float4v acc[8][4];
#pragma unroll
  for (int i = 0; i < 8; i++)
#pragma unroll
    for (int j = 0; j < 4; j++) acc[i][j] = z;

  // staging: thread t -> rows sr0, sr0+128; physical chunk t&3 holds logical
  // chunk (t&3)^f(row), f(row)=(row>>1)&3 = (t>>3)&3 (same for both rows).
  const int sr0 = t >> 2, sr1 = sr0 + 128;
  const int pc = (t & 3) * 8;                          // physical chunk (dest, linear)
  const int scol = ((t & 3) ^ ((t >> 3) & 3)) * 8;     // swizzled global col

#define STGA(rg, kb)                                                                                            \
  {                                                                                                             \
    __builtin_amdgcn_global_load_lds(AS1(Ap + (size_t)sr0 * K + (kb) + scol), AS3(&As[rg][sr0][pc]), 16, 0, 0); \
    __builtin_amdgcn_global_load_lds(AS1(Ap + (size_t)sr1 * K + (kb) + scol), AS3(&As[rg][sr1][pc]), 16, 0, 0); \
  }
#define STGB(rg, kb)                                                                                            \
  {                                                                                                             \
    __builtin_amdgcn_global_load_lds(AS1(Bp + (size_t)sr0 * K + (kb) + scol), AS3(&Bs[rg][sr0][pc]), 16, 0, 0); \
    __builtin_amdgcn_global_load_lds(AS1(Bp + (size_t)sr1 * K + (kb) + scol), AS3(&Bs[rg][sr1][pc]), 16, 0, 0); \
  }
#define VM8 asm volatile("s_waitcnt vmcnt(8)" ::: "memory")
#define VM4 asm volatile("s_waitcnt vmcnt(4)" ::: "memory")
#define VM0 asm volatile("s_waitcnt vmcnt(0)" ::: "memory")

// One phase: 8 swizzled ds_read_b128 -> stage issue -> (vmcnt) -> bar ->
// lgkmcnt(0)+sched_barrier -> setprio(1) 16 MFMA setprio(0) -> bar
#define PH(rg, mq, STG_, VM_)                                                         \
  {                                                                                   \
    short8v a_[4], b_[4];                                                             \
    _Pragma("unroll") for (int i = 0; i < 4; i++) {                                   \
      const int r_ = wm * 128 + ((mq)*4 + i) * 16 + lr;                               \
      a_[i] = *(const short8v*)&As[rg][r_][(g ^ ((r_ >> 1) & 3)) * 8];                \
    }                                                                                 \
    _Pragma("unroll") for (int j = 0; j < 4; j++) {                                   \
      const int r_ = wn * 64 + j * 16 + lr;                                           \
      b_[j] = *(const short8v*)&Bs[rg][r_][(g ^ ((r_ >> 1) & 3)) * 8];                \
    }                                                                                 \
    STG_;                                                                             \
    VM_;                                                                              \
    __builtin_amdgcn_s_barrier();                                                     \
    asm volatile("s_waitcnt lgkmcnt(0)");                                             \
    __builtin_amdgcn_sched_barrier(0);                                                \
    __builtin_amdgcn_s_setprio(1);                                                    \
    _Pragma("unroll") for (int i = 0; i < 4; i++)                                     \
        _Pragma("unroll") for (int j = 0; j < 4; j++)                                 \
            acc[(mq)*4 + i][j] = MFMA32(a_[i], b_[j], acc[(mq)*4 + i][j]);            \
    __builtin_amdgcn_s_setprio(0);                                                    \
    __builtin_amdgcn_s_barrier();                                                     \
  }

  // prologue: stage K-subtiles 0,1,2 into rings 0,1,2 (12 loads); ring0 landed
  STGA(0, 0);
  STGB(0, 0);
  STGA(1, 32);
  STGB(1, 32);
  STGA(2, 64);
  STGB(2, 64);
  VM8;
  __builtin_amdgcn_s_barrier();

  for (int r = 0; r < 29; ++r) {
    const int rg = r & 3, rs = (r + 3) & 3, kb = (r + 3) * 32;
    PH(rg, 0, STGA(rs, kb), );
    PH(rg, 1, STGB(rs, kb), VM8);  // retires subtile r+1's 4 loads (12 -> 8 outstanding)
  }
  // tail: r=29 (ring 1), r=30 (ring 2), r=31 (ring 3); no staging left
  PH(1, 0, , );
  PH(1, 1, , VM4);  // ring 2 (subtile 30) landed
  PH(2, 0, , );
  PH(2, 1, , VM0);  // ring 3 (subtile 31) landed (single full drain, tail only)
  PH(3, 0, , );
  PH(3, 1, , );

#undef PH
#undef STGA
#undef STGB

  const int colb = nb * 256 + wn * 64;
  const int rowb = mb * 256 + wm * 128;
#pragma unroll
  for (int j = 0; j < 4; j++) {
    const int col = colb + j * 16 + lr;
    const float bv = bias[col];
#pragma unroll
    for (int i = 0; i < 8; i++) {
      const int row0 = rowb + i * 16 + g * 4;
#pragma unroll
      for (int r = 0; r < 4; r++)
        C[(size_t)(row0 + r) * 1024 + col] = f2bf((acc[i][j][r] + bv) * scale);
    }
  }
}

// ---------------- GEMM (output projection): 128x128 tile, 2-phase dbuf ----------------

template <int OUTF32>
__global__ __launch_bounds__(256) void gemm_bt(
    const u16* __restrict__ A,
    const u16* __restrict__ B0, const u16* __restrict__ B1, const u16* __restrict__ B2,
    const float* __restrict__ bias0, const float* __restrict__ bias1, const float* __restrict__ bias2,
    void* __restrict__ C0, void* __restrict__ C1, void* __restrict__ C2,
    float sc0, float sc1, float sc2) {
  constexpr int K = 1024;
  __shared__ u16 As[2][128 * 32];
  __shared__ u16 Bs[2][128 * 32];

  const int t = threadIdx.x;
  const int lane = t & 63, wid = t >> 6;
  const int wr = wid >> 1, wc = wid & 1;
  const int lr = lane & 15, g = lane >> 4;

  const int seg = blockIdx.y >> 3, nb = blockIdx.y & 7, mb = blockIdx.x;
  const u16* B = seg == 0 ? B0 : (seg == 1 ? B1 : B2);
  const float* bias = seg == 0 ? bias0 : (seg == 1 ? bias1 : bias2);
  void* C = seg == 0 ? C0 : (seg == 1 ? C1 : C2);
  const float scale = seg == 0 ? sc0 : (seg == 1 ? sc1 : sc2);

  const u16* Ap = A + (size_t)mb * 128 * K;
  const u16* Bp = B + (size_t)nb * 128 * K;

  float4v z = {0.f, 0.f, 0.f, 0.f};
  float4v acc[4][4];
#pragma unroll
  for (int i = 0; i < 4; i++)
#pragma unroll
    for (int j = 0; j < 4; j++) acc[i][j] = z;

  const int r0 = t >> 2, c0 = (t & 3) * 8;

#define GSTAGE(u, kk)                                                                                          \
  do {                                                                                                         \
    __builtin_amdgcn_global_load_lds(AS1(Ap + (size_t)r0 * K + (kk) + c0), AS3(&As[u][t * 8]), 16, 0, 0);      \
    __builtin_amdgcn_global_load_lds(AS1(Ap + (size_t)(r0 + 64) * K + (kk) + c0), AS3(&As[u][(t + 256) * 8]),  \
                                     16, 0, 0);                                                                \
    __builtin_amdgcn_global_load_lds(AS1(Bp + (size_t)r0 * K + (kk) + c0), AS3(&Bs[u][t * 8]), 16, 0, 0);      \
    __builtin_amdgcn_global_load_lds(AS1(Bp + (size_t)(r0 + 64) * K + (kk) + c0), AS3(&Bs[u][(t + 256) * 8]),  \
                                     16, 0, 0);                                                                \
  } while (0)

  GSTAGE(0, 0);
  int cur = 0;
  for (int k0 = 0; k0 < K; k0 += 32) {
    __syncthreads();
    if (k0 + 32 < K) GSTAGE(cur ^ 1, k0 + 32);

    const u16* Au = &As[cur][0];
    const u16* Bu = &Bs[cur][0];
    short8v af[4], bfr[4];
#pragma unroll
    for (int mi = 0; mi < 4; mi++) af[mi] = *(const short8v*)(Au + (wr * 64 + mi * 16 + lr) * 32 + g * 8);
#pragma unroll
    for (int ni = 0; ni < 4; ni++) bfr[ni] = *(const short8v*)(Bu + (wc * 64 + ni * 16 + lr) * 32 + g * 8);
    __builtin_amdgcn_s_setprio(1);
#pragma unroll
    for (int mi = 0; mi < 4; mi++)
#pragma unroll
      for (int ni = 0; ni < 4; ni++) acc[mi][ni] = MFMA32(af[mi], bfr[ni], acc[mi][ni]);
    __builtin_amdgcn_s_setprio(0);
    __syncthreads();
    cur ^= 1;
  }
#undef GSTAGE

  const int colb = nb * 128 + wc * 64;
  const int rowb = mb * 128 + wr * 64;
#pragma unroll
  for (int ni = 0; ni < 4; ni++) {
    const int col = colb + ni * 16 + lr;
    const float bv = bias[col];
#pragma unroll
    for (int mi = 0; mi < 4; mi++) {
      const int row0 = rowb + mi * 16 + g * 4;
      float4v a = acc[mi][ni];
      if (OUTF32) {
        float* Cf = (float*)C;
#pragma unroll
        for (int r = 0; r < 4; r++) Cf[(size_t)(row0 + r) * 1024 + col] = (a[r] + bv) * scale;
      } else {
        u16* Cb = (u16*)C;
#pragma unroll
        for (int r = 0; r < 4; r++) Cb[(size_t)(row0 + r) * 1024 + col] = f2bf((a[r] + bv) * scale);
      }
    }
  }
}

// ---------------- Flash attention (R2 config: QBLK=64) ----------------

__global__ __launch_bounds__(256) void attn_fwd(const u16* __restrict__ Qm, const u16* __restrict__ Km,
                                                const u16* __restrict__ Vm, u16* __restrict__ Om) {
  __shared__ u16 Ks[2][64 * 64];
  __shared__ u16 Vs[2][64 * 64];

  const int t = threadIdx.x;
  const int lane = t & 63, w = t >> 6;
  const int lr = lane & 15, g = lane >> 4;
  const int qb = blockIdx.x, pair = blockIdx.y;
  const int b = pair >> 4, a = pair & 15;

  const int qrow = qb * 64 + w * 16 + lr;
  const size_t qoff = ((size_t)(b * 1024 + qrow)) * 1024 + a * 64;
  const short8v qf0 = *(const short8v*)(Qm + qoff + g * 8);
  const short8v qf1 = *(const short8v*)(Qm + qoff + 32 + g * 8);

  float4v z = {0.f, 0.f, 0.f, 0.f};
  float4v ot[4];
#pragma unroll
  for (int i = 0; i < 4; i++) ot[i] = z;
  float mrun = -3.0e38f, lsum = 0.f;

  const u16* Kb = Km + ((size_t)b * 1024) * 1024 + a * 64;
  const u16* Vb = Vm + ((size_t)b * 1024) * 1024 + a * 64;

  const int kr0 = t >> 3, kr1 = kr0 + 32;
  const int kc0 = ((t & 7) ^ (kr0 & 7)) * 8;
  const int vr0 = (t >> 1) & 63;
  const int vc0 = (t >> 7) * 16 + (t & 1) * 8;

#define ASTAGE(u, kt)                                                                                             \
  do {                                                                                                            \
    __builtin_amdgcn_global_load_lds(AS1(Kb + (size_t)((kt) + kr0) * 1024 + kc0), AS3(&Ks[u][t * 8]), 16, 0, 0);  \
    __builtin_amdgcn_global_load_lds(AS1(Kb + (size_t)((kt) + kr1) * 1024 + kc0), AS3(&Ks[u][(t + 256) * 8]),     \
                                     16, 0, 0);                                                                   \
    __builtin_amdgcn_global_load_lds(AS1(Vb + (size_t)((kt) + vr0) * 1024 + vc0), AS3(&Vs[u][t * 8]), 16, 0, 0);  \
    __builtin_amdgcn_global_load_lds(AS1(Vb + (size_t)((kt) + vr0) * 1024 + vc0 + 32), AS3(&Vs[u][(t + 256) * 8]),\
                                     16, 0, 0);                                                                   \
  } while (0)

  const unsigned vsbase = (unsigned)(uintptr_t)AS3(&Vs[0][0]);
  const unsigned vlane = (unsigned)((g * 4 + (lr >> 2)) * 32 + (lane & 3) * 8);

  ASTAGE(0, 0);
  int cur = 0;
  for (int kt = 0; kt < 1024; kt += 64) {
    __syncthreads();
    if (kt + 64 < 1024) ASTAGE(cur ^ 1, kt + 64);

    const u16* Ku = &Ks[cur][0];
    float4v st[4];
#pragma unroll
    for (int jt = 0; jt < 4; jt++) {
      float4v s = z;
      const int row = jt * 16 + lr;
      const int rsw = (row & 7) << 4;
      __builtin_amdgcn_s_setprio(1);
#pragma unroll
      for (int ks = 0; ks < 2; ks++) {
        const int baddr = (row * 128 + (ks * 4 + g) * 16) ^ rsw;
        short8v kf = *(const short8v*)((const char*)Ku + baddr);
        s = MFMA32(kf, ks ? qf1 : qf0, s);
      }
      __builtin_amdgcn_s_setprio(0);
      st[jt] = s;
    }

    float tm = st[0][0];
#pragma unroll
    for (int jt = 0; jt < 4; jt++)
#pragma unroll
      for (int r = 0; r < 4; r++) tm = fmaxf(tm, st[jt][r]);
    tm = fmaxf(tm, __shfl_xor(tm, 16));
    tm = fmaxf(tm, __shfl_xor(tm, 32));
    if (!__all(tm - mrun <= 8.f)) {
      const float mnew = fmaxf(mrun, tm);
      const float sca = exp2f(mrun - mnew);
      lsum *= sca;
#pragma unroll
      for (int d = 0; d < 4; d++)
#pragma unroll
        for (int r = 0; r < 4; r++) ot[d][r] *= sca;
      mrun = mnew;
    }
    float p[16];
    float ts = 0.f;
#pragma unroll
    for (int jt = 0; jt < 4; jt++)
#pragma unroll
      for (int r = 0; r < 4; r++) {
        const float pv = exp2f(st[jt][r] - mrun);
        p[jt * 4 + r] = pv;
        ts += pv;
      }
    ts += __shfl_xor(ts, 16);
    ts += __shfl_xor(ts, 32);
    lsum += ts;

    short4v pf[4];
#pragma unroll
    for (int jt = 0; jt < 4; jt++) {
      unsigned lo = cvtpk(p[jt * 4 + 0], p[jt * 4 + 1]);
      unsigned hi = cvtpk(p[jt * 4 + 2], p[jt * 4 + 3]);
      unsigned u2[2] = {lo, hi};
      pf[jt] = __builtin_bit_cast(short4v, *(unsigned long long*)u2);
    }

    unsigned va = vsbase + (unsigned)cur * 8192u + vlane;
#pragma unroll
    for (int jt = 0; jt < 4; jt++) {
      short4v vf0, vf1, vf2, vf3;
      TR4(vf0, vf1, vf2, vf3, va);
      __builtin_amdgcn_s_setprio(1);
      ot[0] = MFMA16(vf0, pf[jt], ot[0]);
      ot[1] = MFMA16(vf1, pf[jt], ot[1]);
      ot[2] = MFMA16(vf2, pf[jt], ot[2]);
      ot[3] = MFMA16(vf3, pf[jt], ot[3]);
      __builtin_amdgcn_s_setprio(0);
      va += 512u;
    }

    __syncthreads();
    cur ^= 1;
  }
#undef ASTAGE

  const float inv = 1.f / lsum;
  u16* Op = Om + ((size_t)(b * 1024 + qrow)) * 1024 + a * 64;
#pragma unroll
  for (int dblk = 0; dblk < 4; dblk++) {
    short4v o4;
#pragma unroll
    for (int r = 0; r < 4; r++) o4[r] = (short)f2bf(ot[dblk][r] * inv);
    *(short4v*)(Op + dblk * 16 + g * 4) = o4;
  }
}

// ---------------- launch ----------------

extern "C" void kernel_launch(void* const* d_in, const int* in_sizes, int n_in,
                              void* d_out, int out_size, void* d_ws, size_t ws_size,
                              hipStream_t stream) {
  (void)in_sizes; (void)n_in; (void)out_size; (void)ws_size;
  const float* x = (const float*)d_in[0];
  const float* Wq = (const float*)d_in[1];
  const float* bq = (const float*)d_in[2];
  const float* Wk = (const float*)d_in[3];
  const float* bk = (const float*)d_in[4];
  const float* Wv = (const float*)d_in[5];
  const float* bv = (const float*)d_in[6];
  const float* Wo = (const float*)d_in[7];
  const float* bo = (const float*)d_in[8];
  float* out = (float*)d_out;

  char* ws = (char*)d_ws;
  const size_t MB = 1u << 20;
  u16* xb = (u16*)(ws + 0 * MB);
  u16* Wqb = (u16*)(ws + 8 * MB);
  u16* Wkb = (u16*)(ws + 10 * MB);
  u16* Wvb = (u16*)(ws + 12 * MB);
  u16* Wob = (u16*)(ws + 14 * MB);
  u16* Qb = (u16*)(ws + 16 * MB);
  u16* Kb = (u16*)(ws + 24 * MB);
  u16* Vb = (u16*)(ws + 32 * MB);
  u16* Ab = (u16*)(ws + 40 * MB);

  const float csc = 1.4426950408889634f / 8.0f;  // log2(e)/sqrt(HEAD_DIM)

  cast1_k<<<4096, 256, 0, stream>>>(x, xb);
  cast4_k<<<dim3(1024, 4), 256, 0, stream>>>(Wq, Wk, Wv, Wo, Wqb, Wkb, Wvb, Wob);
  gemm256<<<192, 512, 0, stream>>>(xb, Wqb, Wkb, Wvb, bq, bk, bv, Qb, Kb, Vb, csc, 1.f, 1.f);
  attn_fwd<<<dim3(16, 64), 256, 0, stream>>>(Qb, Kb, Vb, Ab);
  gemm_bt<1><<<dim3(32, 8), 256, 0, stream>>>(Ab, Wob, Wob, Wob, bo, bo, bo, out, out, out, 1.f, 1.f, 1.f);
}